// Round 1
// baseline (936.775 us; speedup 1.0000x reference)
//
#include <hip/hip_runtime.h>

#define NN 40000
#define NE 640000
#define HID 128
#define NCLS 10
#define NGRAPH 16

// ---------------- degree count ----------------
__global__ void k_count_deg(const int* __restrict__ dst, int* __restrict__ deg, int n) {
    int e = blockIdx.x * blockDim.x + threadIdx.x;
    if (e < n) atomicAdd(&deg[dst[e]], 1);
}

// ---------------- single-block prefix scan (exclusive) over deg -> row_start[0..n] ----------------
__global__ __launch_bounds__(1024) void k_scan(const int* __restrict__ deg, int* __restrict__ row_start, int n) {
    __shared__ int wsum[16];
    __shared__ int carry_s;
    int tid = threadIdx.x, lane = tid & 63, wid = tid >> 6;
    if (tid == 0) carry_s = 0;
    __syncthreads();
    for (int base = 0; base < n; base += 1024) {
        int i = base + tid;
        int v = (i < n) ? deg[i] : 0;
        int sv = v;
        #pragma unroll
        for (int off = 1; off < 64; off <<= 1) {
            int t = __shfl_up(sv, off);
            if (lane >= off) sv += t;
        }
        if (lane == 63) wsum[wid] = sv;
        __syncthreads();
        if (wid == 0) {
            int ws = (lane < 16) ? wsum[lane] : 0;
            #pragma unroll
            for (int off = 1; off < 16; off <<= 1) {
                int t = __shfl_up(ws, off);
                if (lane >= off) ws += t;
            }
            if (lane < 16) wsum[lane] = ws;
        }
        __syncthreads();
        int excl = carry_s + (wid > 0 ? wsum[wid - 1] : 0) + (sv - v);
        if (i < n) row_start[i] = excl;
        __syncthreads();
        if (tid == 0) carry_s += wsum[15];
        __syncthreads();
    }
    if (threadIdx.x == 0) row_start[n] = carry_s;
}

// ---------------- CSR bucket fill ----------------
__global__ void k_fill_csr(const int* __restrict__ src, const int* __restrict__ dst,
                           const int* __restrict__ row_start, int* __restrict__ fill,
                           int* __restrict__ csr_src, int n) {
    int e = blockIdx.x * blockDim.x + threadIdx.x;
    if (e < n) {
        int d = dst[e];
        int pos = atomicAdd(&fill[d], 1);
        csr_src[row_start[d] + pos] = src[e];
    }
}

// ---------------- norm = max(deg,1)^-0.5 ----------------
__global__ void k_norm(const int* __restrict__ deg, float* __restrict__ norm, int n) {
    int i = blockIdx.x * blockDim.x + threadIdx.x;
    if (i < n) norm[i] = rsqrtf(fmaxf((float)deg[i], 1.0f));
}

// ---------------- propagation: y[i] = norm[i] * sum_{src in in(i)} norm[src]*x[src] ----------------
// blockDim (32,8): 32 lanes cover 128 cols as float4; 8 nodes per block.
__global__ __launch_bounds__(256) void k_prop(const float* __restrict__ x, const float* __restrict__ norm,
                                              const int* __restrict__ row_start, const int* __restrict__ csr_src,
                                              float* __restrict__ y) {
    int node = blockIdx.x * 8 + threadIdx.y;
    if (node >= NN) return;
    int lane = threadIdx.x;
    float4 acc = make_float4(0.f, 0.f, 0.f, 0.f);
    int s = row_start[node], e = row_start[node + 1];
    for (int i = s; i < e; ++i) {
        int sn = csr_src[i];
        float ns = norm[sn];
        float4 v = *reinterpret_cast<const float4*>(x + (size_t)sn * HID + lane * 4);
        acc.x += ns * v.x; acc.y += ns * v.y; acc.z += ns * v.z; acc.w += ns * v.w;
    }
    float nd = norm[node];
    float4 out = make_float4(nd * acc.x, nd * acc.y, nd * acc.z, nd * acc.w);
    *reinterpret_cast<float4*>(y + (size_t)node * HID + lane * 4) = out;
}

// ---------------- fused concat-GEMM + bias + relu ----------------
// y[row,:] = relu(b + x0[row]@W[0:128] + x1[row]@W[128:256] + x2[row]@W[256:384])
// blockDim (32,8): lane covers 4 cols; 8 rows/block.
__global__ __launch_bounds__(256) void k_gemm_relu(const float* __restrict__ x0, const float* __restrict__ x1,
                                                   const float* __restrict__ x2, const float* __restrict__ W,
                                                   const float* __restrict__ b, float* __restrict__ y) {
    int row = blockIdx.x * 8 + threadIdx.y;
    if (row >= NN) return;
    int lane = threadIdx.x;
    float4 acc = *reinterpret_cast<const float4*>(b + lane * 4);
    const float* xs[3] = { x0 + (size_t)row * HID, x1 + (size_t)row * HID, x2 + (size_t)row * HID };
    #pragma unroll
    for (int blk = 0; blk < 3; ++blk) {
        const float* __restrict__ xp = xs[blk];
        const float* __restrict__ Wp = W + (size_t)blk * HID * HID + lane * 4;
        for (int k = 0; k < HID; ++k) {
            float xv = xp[k];
            float4 w = *reinterpret_cast<const float4*>(Wp + (size_t)k * HID);
            acc.x += xv * w.x; acc.y += xv * w.y; acc.z += xv * w.z; acc.w += xv * w.w;
        }
    }
    acc.x = fmaxf(acc.x, 0.f); acc.y = fmaxf(acc.y, 0.f);
    acc.z = fmaxf(acc.z, 0.f); acc.w = fmaxf(acc.w, 0.f);
    *reinterpret_cast<float4*>(y + (size_t)row * HID + lane * 4) = acc;
}

// ---------------- segment max pool (graph_ids sorted, values >= 0) ----------------
__global__ __launch_bounds__(128) void k_pool(const float* __restrict__ Z, const int* __restrict__ gid,
                                              float* __restrict__ pooled, int n) {
    const int CHUNK = 256;
    int d = threadIdx.x;
    int start = blockIdx.x * CHUNK;
    if (start >= n) return;
    int end = min(start + CHUNK, n);
    float m = 0.0f;
    int cg = gid[start];
    for (int i = start; i < end; ++i) {
        int g = gid[i];
        if (g != cg) {
            atomicMax((unsigned int*)&pooled[cg * HID + d], __float_as_uint(m));
            m = 0.0f; cg = g;
        }
        m = fmaxf(m, Z[(size_t)i * HID + d]);
    }
    atomicMax((unsigned int*)&pooled[cg * HID + d], __float_as_uint(m));
}

// ---------------- final head: out = pooled @ Wc + bc ----------------
__global__ void k_head(const float* __restrict__ pooled, const float* __restrict__ Wc,
                       const float* __restrict__ bc, float* __restrict__ out) {
    int t = threadIdx.x;
    if (t < NGRAPH * NCLS) {
        int g = t / NCLS, c = t % NCLS;
        float acc = bc[c];
        for (int k = 0; k < HID; ++k) acc += pooled[g * HID + k] * Wc[k * NCLS + c];
        out[t] = acc;
    }
}

extern "C" void kernel_launch(void* const* d_in, const int* in_sizes, int n_in,
                              void* d_out, int out_size, void* d_ws, size_t ws_size,
                              hipStream_t stream) {
    const float* h   = (const float*)d_in[0];
    const int*   src = (const int*)d_in[1];
    const int*   dst = (const int*)d_in[2];
    const int*   gid = (const int*)d_in[3];
    const float* W1  = (const float*)d_in[4];
    const float* b1  = (const float*)d_in[5];
    const float* W2  = (const float*)d_in[6];
    const float* b2  = (const float*)d_in[7];
    const float* Wc  = (const float*)d_in[8];
    const float* bc  = (const float*)d_in[9];
    float* out = (float*)d_out;

    char* ws = (char*)d_ws;
    size_t off = 0;
    int*   deg       = (int*)(ws + off);   off += (size_t)NN * 4;          // 160000
    int*   fill      = (int*)(ws + off);   off += (size_t)NN * 4;          // 160000
    int*   row_start = (int*)(ws + off);   off += (size_t)(NN + 4) * 4;    // 160016
    int*   csr_src   = (int*)(ws + off);   off += (size_t)NE * 4;          // 2560000
    float* norm      = (float*)(ws + off); off += (size_t)NN * 4;          // 160000
    float* pooled    = (float*)(ws + off); off += (size_t)NGRAPH * HID * 4; // 8192
    float* B         = (float*)(ws + off); off += (size_t)NN * HID * 4;
    float* C         = (float*)(ws + off); off += (size_t)NN * HID * 4;
    float* Y         = (float*)(ws + off); off += (size_t)NN * HID * 4;
    float* Z         = (float*)(ws + off); off += (size_t)NN * HID * 4;

    // zero deg+fill (contiguous at ws start) and pooled
    hipMemsetAsync(deg, 0, (size_t)NN * 4 * 2, stream);
    hipMemsetAsync(pooled, 0, (size_t)NGRAPH * HID * 4, stream);

    const int EB = 256;
    // CSR build
    k_count_deg<<<(NE + EB - 1) / EB, EB, 0, stream>>>(dst, deg, NE);
    k_scan<<<1, 1024, 0, stream>>>(deg, row_start, NN);
    k_fill_csr<<<(NE + EB - 1) / EB, EB, 0, stream>>>(src, dst, row_start, fill, csr_src, NE);
    k_norm<<<(NN + EB - 1) / EB, EB, 0, stream>>>(deg, norm, NN);

    dim3 blk(32, 8);
    int nblocks = (NN + 7) / 8;

    // layer 1: feats = [h, P h, P^2 h]
    k_prop<<<nblocks, blk, 0, stream>>>(h, norm, row_start, csr_src, B);
    k_prop<<<nblocks, blk, 0, stream>>>(B, norm, row_start, csr_src, C);
    k_gemm_relu<<<nblocks, blk, 0, stream>>>(h, B, C, W1, b1, Y);

    // layer 2
    k_prop<<<nblocks, blk, 0, stream>>>(Y, norm, row_start, csr_src, B);
    k_prop<<<nblocks, blk, 0, stream>>>(B, norm, row_start, csr_src, C);
    k_gemm_relu<<<nblocks, blk, 0, stream>>>(Y, B, C, W2, b2, Z);

    // pool + head
    k_pool<<<(NN + 255) / 256, 128, 0, stream>>>(Z, gid, pooled, NN);
    k_head<<<1, 192, 0, stream>>>(pooled, Wc, bc, out);
}

// Round 2
// 515.430 us; speedup vs baseline: 1.8175x; 1.8175x over previous
//
#include <hip/hip_runtime.h>

#define NN 40000
#define NE 640000
#define HID 128
#define NCLS 10
#define NGRAPH 16

// ---------------- degree count ----------------
__global__ void k_count_deg(const int* __restrict__ dst, int* __restrict__ deg, int n) {
    int e = blockIdx.x * blockDim.x + threadIdx.x;
    if (e < n) atomicAdd(&deg[dst[e]], 1);
}

// ---------------- single-block prefix scan (exclusive) over deg -> row_start[0..n] ----------------
__global__ __launch_bounds__(1024) void k_scan(const int* __restrict__ deg, int* __restrict__ row_start, int n) {
    __shared__ int wsum[16];
    __shared__ int carry_s;
    int tid = threadIdx.x, lane = tid & 63, wid = tid >> 6;
    if (tid == 0) carry_s = 0;
    __syncthreads();
    for (int base = 0; base < n; base += 1024) {
        int i = base + tid;
        int v = (i < n) ? deg[i] : 0;
        int sv = v;
        #pragma unroll
        for (int off = 1; off < 64; off <<= 1) {
            int t = __shfl_up(sv, off);
            if (lane >= off) sv += t;
        }
        if (lane == 63) wsum[wid] = sv;
        __syncthreads();
        if (wid == 0) {
            int ws = (lane < 16) ? wsum[lane] : 0;
            #pragma unroll
            for (int off = 1; off < 16; off <<= 1) {
                int t = __shfl_up(ws, off);
                if (lane >= off) ws += t;
            }
            if (lane < 16) wsum[lane] = ws;
        }
        __syncthreads();
        int excl = carry_s + (wid > 0 ? wsum[wid - 1] : 0) + (sv - v);
        if (i < n) row_start[i] = excl;
        __syncthreads();
        if (tid == 0) carry_s += wsum[15];
        __syncthreads();
    }
    if (threadIdx.x == 0) row_start[n] = carry_s;
}

// ---------------- CSR bucket fill ----------------
__global__ void k_fill_csr(const int* __restrict__ src, const int* __restrict__ dst,
                           const int* __restrict__ row_start, int* __restrict__ fill,
                           int* __restrict__ csr_src, int n) {
    int e = blockIdx.x * blockDim.x + threadIdx.x;
    if (e < n) {
        int d = dst[e];
        int pos = atomicAdd(&fill[d], 1);
        csr_src[row_start[d] + pos] = src[e];
    }
}

// ---------------- norm = max(deg,1)^-0.5 ----------------
__global__ void k_norm(const int* __restrict__ deg, float* __restrict__ norm, int n) {
    int i = blockIdx.x * blockDim.x + threadIdx.x;
    if (i < n) norm[i] = rsqrtf(fmaxf((float)deg[i], 1.0f));
}

// ---------------- propagation: y[i] = norm[i] * sum_{src in in(i)} norm[src]*x[src] ----------------
// blockDim (32,8): 32 lanes cover 128 cols as float4; 8 nodes per block.
// 4-wide edge unroll so the gather chains overlap.
__global__ __launch_bounds__(256) void k_prop(const float* __restrict__ x, const float* __restrict__ norm,
                                              const int* __restrict__ row_start, const int* __restrict__ csr_src,
                                              float* __restrict__ y) {
    int node = blockIdx.x * 8 + threadIdx.y;
    if (node >= NN) return;
    int lane = threadIdx.x;
    float4 acc = make_float4(0.f, 0.f, 0.f, 0.f);
    int s = row_start[node], e = row_start[node + 1];
    int i = s;
    for (; i + 4 <= e; i += 4) {
        int sn0 = csr_src[i], sn1 = csr_src[i + 1], sn2 = csr_src[i + 2], sn3 = csr_src[i + 3];
        float ns0 = norm[sn0], ns1 = norm[sn1], ns2 = norm[sn2], ns3 = norm[sn3];
        float4 v0 = *reinterpret_cast<const float4*>(x + (size_t)sn0 * HID + lane * 4);
        float4 v1 = *reinterpret_cast<const float4*>(x + (size_t)sn1 * HID + lane * 4);
        float4 v2 = *reinterpret_cast<const float4*>(x + (size_t)sn2 * HID + lane * 4);
        float4 v3 = *reinterpret_cast<const float4*>(x + (size_t)sn3 * HID + lane * 4);
        acc.x += ns0 * v0.x + ns1 * v1.x + ns2 * v2.x + ns3 * v3.x;
        acc.y += ns0 * v0.y + ns1 * v1.y + ns2 * v2.y + ns3 * v3.y;
        acc.z += ns0 * v0.z + ns1 * v1.z + ns2 * v2.z + ns3 * v3.z;
        acc.w += ns0 * v0.w + ns1 * v1.w + ns2 * v2.w + ns3 * v3.w;
    }
    for (; i < e; ++i) {
        int sn = csr_src[i];
        float ns = norm[sn];
        float4 v = *reinterpret_cast<const float4*>(x + (size_t)sn * HID + lane * 4);
        acc.x += ns * v.x; acc.y += ns * v.y; acc.z += ns * v.z; acc.w += ns * v.w;
    }
    float nd = norm[node];
    float4 outv = make_float4(nd * acc.x, nd * acc.y, nd * acc.z, nd * acc.w);
    *reinterpret_cast<float4*>(y + (size_t)node * HID + lane * 4) = outv;
}

// ---------------- fused concat-GEMM + bias + relu, LDS-tiled ----------------
// y[row,:] = relu(b + x0[row]@W[0:128] + x1[row]@W[128:256] + x2[row]@W[256:384])
// Block: 32 rows x 128 cols. blockDim (32,8). Thread: 4 rows (r*8+ty) x 4 cols (lane*4).
__global__ __launch_bounds__(256) void k_gemm_relu(const float* __restrict__ x0, const float* __restrict__ x1,
                                                   const float* __restrict__ x2, const float* __restrict__ W,
                                                   const float* __restrict__ b, float* __restrict__ y) {
    __shared__ float sW[32][128];   // 16 KB: W[k-chunk][128]
    __shared__ float sX[32][32];    // 4 KB:  x[row-tile][k-chunk]
    int lane = threadIdx.x;         // 0..31
    int ty = threadIdx.y;           // 0..7
    int tid = ty * 32 + lane;       // 0..255
    int row0 = blockIdx.x * 32;
    const float* xs[3] = { x0, x1, x2 };

    float4 bb = *reinterpret_cast<const float4*>(b + lane * 4);
    float4 acc[4];
    #pragma unroll
    for (int r = 0; r < 4; ++r) acc[r] = bb;

    for (int kb = 0; kb < 12; ++kb) {
        const float* __restrict__ xsrc = xs[kb >> 2];
        int koff = (kb & 3) * 32;
        // stage W chunk: 32x128 = 1024 float4, 4 per thread (fully coalesced)
        const float4* Wp = reinterpret_cast<const float4*>(W + (size_t)kb * 32 * 128);
        float4* sWv = reinterpret_cast<float4*>(&sW[0][0]);
        #pragma unroll
        for (int i = 0; i < 4; ++i) sWv[tid + 256 * i] = Wp[tid + 256 * i];
        // stage X chunk: 32 rows x 32 floats = 256 float4, 1 per thread
        {
            int r = tid >> 3, kp = (tid & 7) * 4;
            reinterpret_cast<float4*>(&sX[0][0])[tid] =
                *reinterpret_cast<const float4*>(xsrc + (size_t)(row0 + r) * HID + koff + kp);
        }
        __syncthreads();
        #pragma unroll
        for (int k4 = 0; k4 < 8; ++k4) {
            float4 xv[4];
            #pragma unroll
            for (int r = 0; r < 4; ++r)
                xv[r] = *reinterpret_cast<const float4*>(&sX[r * 8 + ty][k4 * 4]);
            #pragma unroll
            for (int kk = 0; kk < 4; ++kk) {
                float4 w4 = *reinterpret_cast<const float4*>(&sW[k4 * 4 + kk][lane * 4]);
                #pragma unroll
                for (int r = 0; r < 4; ++r) {
                    float xvv = (kk == 0) ? xv[r].x : (kk == 1) ? xv[r].y : (kk == 2) ? xv[r].z : xv[r].w;
                    acc[r].x += xvv * w4.x; acc[r].y += xvv * w4.y;
                    acc[r].z += xvv * w4.z; acc[r].w += xvv * w4.w;
                }
            }
        }
        __syncthreads();
    }
    #pragma unroll
    for (int r = 0; r < 4; ++r) {
        float4 a = acc[r];
        a.x = fmaxf(a.x, 0.f); a.y = fmaxf(a.y, 0.f);
        a.z = fmaxf(a.z, 0.f); a.w = fmaxf(a.w, 0.f);
        *reinterpret_cast<float4*>(y + (size_t)(row0 + r * 8 + ty) * HID + lane * 4) = a;
    }
}

// ---------------- segment max pool (graph_ids sorted, values >= 0) ----------------
__global__ __launch_bounds__(128) void k_pool(const float* __restrict__ Z, const int* __restrict__ gid,
                                              float* __restrict__ pooled, int n) {
    const int CHUNK = 256;
    int d = threadIdx.x;
    int start = blockIdx.x * CHUNK;
    if (start >= n) return;
    int end = min(start + CHUNK, n);
    float m = 0.0f;
    int cg = gid[start];
    for (int i = start; i < end; ++i) {
        int g = gid[i];
        if (g != cg) {
            atomicMax((unsigned int*)&pooled[cg * HID + d], __float_as_uint(m));
            m = 0.0f; cg = g;
        }
        m = fmaxf(m, Z[(size_t)i * HID + d]);
    }
    atomicMax((unsigned int*)&pooled[cg * HID + d], __float_as_uint(m));
}

// ---------------- final head: out = pooled @ Wc + bc ----------------
__global__ void k_head(const float* __restrict__ pooled, const float* __restrict__ Wc,
                       const float* __restrict__ bc, float* __restrict__ out) {
    int t = threadIdx.x;
    if (t < NGRAPH * NCLS) {
        int g = t / NCLS, c = t % NCLS;
        float acc = bc[c];
        for (int k = 0; k < HID; ++k) acc += pooled[g * HID + k] * Wc[k * NCLS + c];
        out[t] = acc;
    }
}

extern "C" void kernel_launch(void* const* d_in, const int* in_sizes, int n_in,
                              void* d_out, int out_size, void* d_ws, size_t ws_size,
                              hipStream_t stream) {
    const float* h   = (const float*)d_in[0];
    const int*   src = (const int*)d_in[1];
    const int*   dst = (const int*)d_in[2];
    const int*   gid = (const int*)d_in[3];
    const float* W1  = (const float*)d_in[4];
    const float* b1  = (const float*)d_in[5];
    const float* W2  = (const float*)d_in[6];
    const float* b2  = (const float*)d_in[7];
    const float* Wc  = (const float*)d_in[8];
    const float* bc  = (const float*)d_in[9];
    float* out = (float*)d_out;

    char* ws = (char*)d_ws;
    size_t off = 0;
    int*   deg       = (int*)(ws + off);   off += (size_t)NN * 4;
    int*   fill      = (int*)(ws + off);   off += (size_t)NN * 4;
    int*   row_start = (int*)(ws + off);   off += (size_t)(NN + 4) * 4;
    int*   csr_src   = (int*)(ws + off);   off += (size_t)NE * 4;
    float* norm      = (float*)(ws + off); off += (size_t)NN * 4;
    float* pooled    = (float*)(ws + off); off += (size_t)NGRAPH * HID * 4;
    float* B         = (float*)(ws + off); off += (size_t)NN * HID * 4;
    float* C         = (float*)(ws + off); off += (size_t)NN * HID * 4;
    float* Y         = (float*)(ws + off); off += (size_t)NN * HID * 4;
    float* Z         = (float*)(ws + off); off += (size_t)NN * HID * 4;

    hipMemsetAsync(deg, 0, (size_t)NN * 4 * 2, stream);
    hipMemsetAsync(pooled, 0, (size_t)NGRAPH * HID * 4, stream);

    const int EB = 256;
    k_count_deg<<<(NE + EB - 1) / EB, EB, 0, stream>>>(dst, deg, NE);
    k_scan<<<1, 1024, 0, stream>>>(deg, row_start, NN);
    k_fill_csr<<<(NE + EB - 1) / EB, EB, 0, stream>>>(src, dst, row_start, fill, csr_src, NE);
    k_norm<<<(NN + EB - 1) / EB, EB, 0, stream>>>(deg, norm, NN);

    dim3 blk(32, 8);
    int pblocks = (NN + 7) / 8;
    int gblocks = NN / 32;  // 1250

    // layer 1: feats = [h, P h, P^2 h]
    k_prop<<<pblocks, blk, 0, stream>>>(h, norm, row_start, csr_src, B);
    k_prop<<<pblocks, blk, 0, stream>>>(B, norm, row_start, csr_src, C);
    k_gemm_relu<<<gblocks, blk, 0, stream>>>(h, B, C, W1, b1, Y);

    // layer 2
    k_prop<<<pblocks, blk, 0, stream>>>(Y, norm, row_start, csr_src, B);
    k_prop<<<pblocks, blk, 0, stream>>>(B, norm, row_start, csr_src, C);
    k_gemm_relu<<<gblocks, blk, 0, stream>>>(Y, B, C, W2, b2, Z);

    // pool + head
    k_pool<<<(NN + 255) / 256, 128, 0, stream>>>(Z, gid, pooled, NN);
    k_head<<<1, 192, 0, stream>>>(pooled, Wc, bc, out);
}

// Round 3
// 348.198 us; speedup vs baseline: 2.6904x; 1.4803x over previous
//
#include <hip/hip_runtime.h>
#include <hip/hip_bf16.h>

#define NN 40000
#define NE 640000
#define HID 128
#define NCLS 10
#define NGRAPH 16

typedef __attribute__((ext_vector_type(8))) short bf16x8;
typedef __attribute__((ext_vector_type(4))) float f32x4;

__device__ inline float bf2f(unsigned short u) {
    unsigned int x = ((unsigned int)u) << 16;
    return __builtin_bit_cast(float, x);
}
__device__ inline unsigned short f2bf(float f) {
    __hip_bfloat16 h = __float2bfloat16(f);
    return __builtin_bit_cast(unsigned short, h);
}

// ---------------- degree count ----------------
__global__ void k_count_deg(const int* __restrict__ dst, int* __restrict__ deg, int n) {
    int e = blockIdx.x * blockDim.x + threadIdx.x;
    if (e < n) atomicAdd(&deg[dst[e]], 1);
}

// ---------------- hierarchical scan: per-block exclusive scan of 1024 ----------------
__global__ __launch_bounds__(1024) void k_scan1(const int* __restrict__ deg, int* __restrict__ row_start,
                                                int* __restrict__ partial) {
    __shared__ int wsum[16];
    int tid = threadIdx.x, lane = tid & 63, wid = tid >> 6;
    int i = blockIdx.x * 1024 + tid;
    int v = (i < NN) ? deg[i] : 0;
    int sv = v;
    #pragma unroll
    for (int off = 1; off < 64; off <<= 1) {
        int t = __shfl_up(sv, off);
        if (lane >= off) sv += t;
    }
    if (lane == 63) wsum[wid] = sv;
    __syncthreads();
    if (wid == 0) {
        int ws = (lane < 16) ? wsum[lane] : 0;
        #pragma unroll
        for (int off = 1; off < 16; off <<= 1) {
            int t = __shfl_up(ws, off);
            if (lane >= off) ws += t;
        }
        if (lane < 16) wsum[lane] = ws;
    }
    __syncthreads();
    int excl = (wid > 0 ? wsum[wid - 1] : 0) + (sv - v);
    if (i < NN) row_start[i] = excl;
    if (tid == 0) partial[blockIdx.x] = wsum[15];
}

__global__ void k_scan2(const int* __restrict__ partial, int* __restrict__ offs, int* __restrict__ row_start, int nb) {
    if (threadIdx.x == 0) {
        int acc = 0;
        for (int j = 0; j < nb; ++j) { offs[j] = acc; acc += partial[j]; }
        row_start[NN] = acc;
    }
}

__global__ __launch_bounds__(1024) void k_scan3(int* __restrict__ row_start, const int* __restrict__ offs) {
    int i = blockIdx.x * 1024 + threadIdx.x;
    if (i < NN) row_start[i] += offs[blockIdx.x];
}

// ---------------- CSR bucket fill ----------------
__global__ void k_fill_csr(const int* __restrict__ src, const int* __restrict__ dst,
                           const int* __restrict__ row_start, int* __restrict__ fill,
                           int* __restrict__ csr_src, int n) {
    int e = blockIdx.x * blockDim.x + threadIdx.x;
    if (e < n) {
        int d = dst[e];
        int pos = atomicAdd(&fill[d], 1);
        csr_src[row_start[d] + pos] = src[e];
    }
}

// ---------------- norm = max(deg,1)^-0.5 ----------------
__global__ void k_norm(const int* __restrict__ deg, float* __restrict__ norm, int n) {
    int i = blockIdx.x * blockDim.x + threadIdx.x;
    if (i < n) norm[i] = rsqrtf(fmaxf((float)deg[i], 1.0f));
}

// ---------------- converts ----------------
__global__ void k_cvt_h(const float* __restrict__ h, unsigned short* __restrict__ hb) {
    int i = blockIdx.x * 256 + threadIdx.x;
    if (i < NN * HID / 4) {
        float4 v = reinterpret_cast<const float4*>(h)[i];
        ushort4 o;
        o.x = f2bf(v.x); o.y = f2bf(v.y); o.z = f2bf(v.z); o.w = f2bf(v.w);
        reinterpret_cast<ushort4*>(hb)[i] = o;
    }
}

// W[384][128] fp32 -> Wt[128][384] bf16
__global__ void k_cvt_wt(const float* __restrict__ W, unsigned short* __restrict__ Wt) {
    int t = blockIdx.x * 256 + threadIdx.x;
    if (t < 384 * HID) {
        int c = t / 384, k = t % 384;
        Wt[t] = f2bf(W[(size_t)k * HID + c]);
    }
}

// ---------------- propagation (bf16 storage, fp32 accum) ----------------
// blockDim (32,8): 32 lanes x ushort4 (8B) cover 128 cols; 8 nodes/block.
__global__ __launch_bounds__(256) void k_prop_bf(const unsigned short* __restrict__ x, const float* __restrict__ norm,
                                                 const int* __restrict__ row_start, const int* __restrict__ csr_src,
                                                 unsigned short* __restrict__ y) {
    int node = blockIdx.x * 8 + threadIdx.y;
    if (node >= NN) return;
    int lane = threadIdx.x;
    float a0 = 0.f, a1 = 0.f, a2 = 0.f, a3 = 0.f;
    int s = row_start[node], e = row_start[node + 1];
    int i = s;
    for (; i + 4 <= e; i += 4) {
        int sn0 = csr_src[i], sn1 = csr_src[i + 1], sn2 = csr_src[i + 2], sn3 = csr_src[i + 3];
        float ns0 = norm[sn0], ns1 = norm[sn1], ns2 = norm[sn2], ns3 = norm[sn3];
        ushort4 v0 = *reinterpret_cast<const ushort4*>(x + (size_t)sn0 * HID + lane * 4);
        ushort4 v1 = *reinterpret_cast<const ushort4*>(x + (size_t)sn1 * HID + lane * 4);
        ushort4 v2 = *reinterpret_cast<const ushort4*>(x + (size_t)sn2 * HID + lane * 4);
        ushort4 v3 = *reinterpret_cast<const ushort4*>(x + (size_t)sn3 * HID + lane * 4);
        a0 += ns0 * bf2f(v0.x) + ns1 * bf2f(v1.x) + ns2 * bf2f(v2.x) + ns3 * bf2f(v3.x);
        a1 += ns0 * bf2f(v0.y) + ns1 * bf2f(v1.y) + ns2 * bf2f(v2.y) + ns3 * bf2f(v3.y);
        a2 += ns0 * bf2f(v0.z) + ns1 * bf2f(v1.z) + ns2 * bf2f(v2.z) + ns3 * bf2f(v3.z);
        a3 += ns0 * bf2f(v0.w) + ns1 * bf2f(v1.w) + ns2 * bf2f(v2.w) + ns3 * bf2f(v3.w);
    }
    for (; i < e; ++i) {
        int sn = csr_src[i];
        float ns = norm[sn];
        ushort4 v = *reinterpret_cast<const ushort4*>(x + (size_t)sn * HID + lane * 4);
        a0 += ns * bf2f(v.x); a1 += ns * bf2f(v.y); a2 += ns * bf2f(v.z); a3 += ns * bf2f(v.w);
    }
    float nd = norm[node];
    ushort4 o;
    o.x = f2bf(nd * a0); o.y = f2bf(nd * a1); o.z = f2bf(nd * a2); o.w = f2bf(nd * a3);
    *reinterpret_cast<ushort4*>(y + (size_t)node * HID + lane * 4) = o;
}

// ---------------- MFMA GEMM: y = relu([x0|x1|x2](bf16) @ W + b), W as Wt[col][k] bf16 ----------------
// grid 1250 x 128 threads (2 waves). Block = 32 rows; wave = 16 rows x 128 cols.
// Per wave: 8 col-frags of 16; K = 384 in chunks of 32.
__global__ __launch_bounds__(128) void k_gemm_mfma(const unsigned short* __restrict__ x0,
                                                   const unsigned short* __restrict__ x1,
                                                   const unsigned short* __restrict__ x2,
                                                   const unsigned short* __restrict__ Wt,
                                                   const float* __restrict__ bias,
                                                   unsigned short* __restrict__ y) {
    int tid = threadIdx.x;
    int wave = tid >> 6;
    int lane = tid & 63;
    int r = lane & 15, kg = lane >> 4;
    int row0 = blockIdx.x * 32 + wave * 16;
    const unsigned short* xs[3] = { x0, x1, x2 };

    f32x4 acc[8];
    #pragma unroll
    for (int cf = 0; cf < 8; ++cf) acc[cf] = (f32x4){0.f, 0.f, 0.f, 0.f};

    #pragma unroll
    for (int kseg = 0; kseg < 3; ++kseg) {
        const unsigned short* __restrict__ xp = xs[kseg] + (size_t)(row0 + r) * HID;
        #pragma unroll
        for (int kb = 0; kb < 4; ++kb) {
            bf16x8 afrag = *reinterpret_cast<const bf16x8*>(xp + kb * 32 + kg * 8);
            #pragma unroll
            for (int cf = 0; cf < 8; ++cf) {
                bf16x8 bfrag = *reinterpret_cast<const bf16x8*>(
                    Wt + (size_t)(cf * 16 + r) * 384 + kseg * 128 + kb * 32 + kg * 8);
                acc[cf] = __builtin_amdgcn_mfma_f32_16x16x32_bf16(afrag, bfrag, acc[cf], 0, 0, 0);
            }
        }
    }
    // epilogue: D layout col = lane&15, row = (lane>>4)*4 + v
    int orow = row0 + (lane >> 4) * 4;
    int colr = lane & 15;
    #pragma unroll
    for (int cf = 0; cf < 8; ++cf) {
        int col = cf * 16 + colr;
        float bb = bias[col];
        #pragma unroll
        for (int v = 0; v < 4; ++v) {
            float val = fmaxf(acc[cf][v] + bb, 0.f);
            y[(size_t)(orow + v) * HID + col] = f2bf(val);
        }
    }
}

// ---------------- segment max pool (bf16 in, fp32 out; gid sorted; values >= 0) ----------------
__global__ __launch_bounds__(128) void k_pool_bf(const unsigned short* __restrict__ Z, const int* __restrict__ gid,
                                                 float* __restrict__ pooled, int n) {
    const int CHUNK = 256;
    int d = threadIdx.x;
    int start = blockIdx.x * CHUNK;
    if (start >= n) return;
    int end = min(start + CHUNK, n);
    float m = 0.0f;
    int cg = gid[start];
    for (int i = start; i < end; ++i) {
        int g = gid[i];
        if (g != cg) {
            atomicMax((unsigned int*)&pooled[cg * HID + d], __float_as_uint(m));
            m = 0.0f; cg = g;
        }
        m = fmaxf(m, bf2f(Z[(size_t)i * HID + d]));
    }
    atomicMax((unsigned int*)&pooled[cg * HID + d], __float_as_uint(m));
}

// ---------------- final head: out = pooled @ Wc + bc ----------------
__global__ void k_head(const float* __restrict__ pooled, const float* __restrict__ Wc,
                       const float* __restrict__ bc, float* __restrict__ out) {
    int t = threadIdx.x;
    if (t < NGRAPH * NCLS) {
        int g = t / NCLS, c = t % NCLS;
        float acc = bc[c];
        for (int k = 0; k < HID; ++k) acc += pooled[g * HID + k] * Wc[k * NCLS + c];
        out[t] = acc;
    }
}

extern "C" void kernel_launch(void* const* d_in, const int* in_sizes, int n_in,
                              void* d_out, int out_size, void* d_ws, size_t ws_size,
                              hipStream_t stream) {
    const float* h   = (const float*)d_in[0];
    const int*   src = (const int*)d_in[1];
    const int*   dst = (const int*)d_in[2];
    const int*   gid = (const int*)d_in[3];
    const float* W1  = (const float*)d_in[4];
    const float* b1  = (const float*)d_in[5];
    const float* W2  = (const float*)d_in[6];
    const float* b2  = (const float*)d_in[7];
    const float* Wc  = (const float*)d_in[8];
    const float* bc  = (const float*)d_in[9];
    float* out = (float*)d_out;

    char* ws = (char*)d_ws;
    size_t off = 0;
    auto alloc = [&](size_t bytes) { void* p = ws + off; off = (off + bytes + 63) & ~(size_t)63; return p; };
    int*   deg       = (int*)alloc((size_t)NN * 4);
    int*   fill      = (int*)alloc((size_t)NN * 4);
    int*   row_start = (int*)alloc((size_t)(NN + 1) * 4);
    int*   csr_src   = (int*)alloc((size_t)NE * 4);
    float* norm      = (float*)alloc((size_t)NN * 4);
    int*   partial   = (int*)alloc(64 * 4);
    int*   offs      = (int*)alloc(64 * 4);
    float* pooled    = (float*)alloc((size_t)NGRAPH * HID * 4);
    unsigned short* W1t = (unsigned short*)alloc((size_t)384 * HID * 2);
    unsigned short* W2t = (unsigned short*)alloc((size_t)384 * HID * 2);
    unsigned short* hb  = (unsigned short*)alloc((size_t)NN * HID * 2);
    unsigned short* Bb  = (unsigned short*)alloc((size_t)NN * HID * 2);
    unsigned short* Cb  = (unsigned short*)alloc((size_t)NN * HID * 2);
    unsigned short* Yb  = (unsigned short*)alloc((size_t)NN * HID * 2);
    unsigned short* Zb  = (unsigned short*)alloc((size_t)NN * HID * 2);

    hipMemsetAsync(deg, 0, (size_t)NN * 4 * 2, stream);   // deg + fill contiguous
    hipMemsetAsync(pooled, 0, (size_t)NGRAPH * HID * 4, stream);

    const int EB = 256;
    const int SCAN_BLOCKS = (NN + 1023) / 1024;  // 40
    k_count_deg<<<(NE + EB - 1) / EB, EB, 0, stream>>>(dst, deg, NE);
    k_scan1<<<SCAN_BLOCKS, 1024, 0, stream>>>(deg, row_start, partial);
    k_scan2<<<1, 64, 0, stream>>>(partial, offs, row_start, SCAN_BLOCKS);
    k_scan3<<<SCAN_BLOCKS, 1024, 0, stream>>>(row_start, offs);
    k_fill_csr<<<(NE + EB - 1) / EB, EB, 0, stream>>>(src, dst, row_start, fill, csr_src, NE);
    k_norm<<<(NN + EB - 1) / EB, EB, 0, stream>>>(deg, norm, NN);

    k_cvt_h<<<(NN * HID / 4 + 255) / 256, 256, 0, stream>>>(h, hb);
    k_cvt_wt<<<(384 * HID + 255) / 256, 256, 0, stream>>>(W1, W1t);
    k_cvt_wt<<<(384 * HID + 255) / 256, 256, 0, stream>>>(W2, W2t);

    dim3 pblk(32, 8);
    int pblocks = (NN + 7) / 8;
    int gblocks = NN / 32;  // 1250

    // layer 1
    k_prop_bf<<<pblocks, pblk, 0, stream>>>(hb, norm, row_start, csr_src, Bb);
    k_prop_bf<<<pblocks, pblk, 0, stream>>>(Bb, norm, row_start, csr_src, Cb);
    k_gemm_mfma<<<gblocks, 128, 0, stream>>>(hb, Bb, Cb, W1t, b1, Yb);

    // layer 2 (reuse Bb/Cb)
    k_prop_bf<<<pblocks, pblk, 0, stream>>>(Yb, norm, row_start, csr_src, Bb);
    k_prop_bf<<<pblocks, pblk, 0, stream>>>(Bb, norm, row_start, csr_src, Cb);
    k_gemm_mfma<<<gblocks, 128, 0, stream>>>(Yb, Bb, Cb, W2t, b2, Zb);

    // pool + head
    k_pool_bf<<<(NN + 255) / 256, 128, 0, stream>>>(Zb, gid, pooled, NN);
    k_head<<<1, 192, 0, stream>>>(pooled, Wc, bc, out);
}

// Round 4
// 284.430 us; speedup vs baseline: 3.2935x; 1.2242x over previous
//
#include <hip/hip_runtime.h>
#include <hip/hip_bf16.h>

#define NN 40000
#define NE 640000
#define HID 128
#define NCLS 10
#define NGRAPH 16

typedef __attribute__((ext_vector_type(8))) short bf16x8;
typedef __attribute__((ext_vector_type(4))) float f32x4;

__device__ inline float bf2f(unsigned short u) {
    unsigned int x = ((unsigned int)u) << 16;
    return __builtin_bit_cast(float, x);
}
__device__ inline unsigned short f2bf(float f) {
    __hip_bfloat16 h = __float2bfloat16(f);
    return __builtin_bit_cast(unsigned short, h);
}

// ---------------- degree count ----------------
__global__ void k_count_deg(const int* __restrict__ dst, int* __restrict__ deg, int n) {
    int e = blockIdx.x * blockDim.x + threadIdx.x;
    if (e < n) atomicAdd(&deg[dst[e]], 1);
}

// ---------------- hierarchical scan ----------------
__global__ __launch_bounds__(1024) void k_scan1(const int* __restrict__ deg, int* __restrict__ row_start,
                                                int* __restrict__ partial) {
    __shared__ int wsum[16];
    int tid = threadIdx.x, lane = tid & 63, wid = tid >> 6;
    int i = blockIdx.x * 1024 + tid;
    int v = (i < NN) ? deg[i] : 0;
    int sv = v;
    #pragma unroll
    for (int off = 1; off < 64; off <<= 1) {
        int t = __shfl_up(sv, off);
        if (lane >= off) sv += t;
    }
    if (lane == 63) wsum[wid] = sv;
    __syncthreads();
    if (wid == 0) {
        int ws = (lane < 16) ? wsum[lane] : 0;
        #pragma unroll
        for (int off = 1; off < 16; off <<= 1) {
            int t = __shfl_up(ws, off);
            if (lane >= off) ws += t;
        }
        if (lane < 16) wsum[lane] = ws;
    }
    __syncthreads();
    int excl = (wid > 0 ? wsum[wid - 1] : 0) + (sv - v);
    if (i < NN) row_start[i] = excl;
    if (tid == 0) partial[blockIdx.x] = wsum[15];
}

__global__ void k_scan2(const int* __restrict__ partial, int* __restrict__ offs, int* __restrict__ row_start, int nb) {
    if (threadIdx.x == 0) {
        int acc = 0;
        for (int j = 0; j < nb; ++j) { offs[j] = acc; acc += partial[j]; }
        row_start[NN] = acc;
    }
}

__global__ __launch_bounds__(1024) void k_scan3(int* __restrict__ row_start, const int* __restrict__ offs) {
    int i = blockIdx.x * 1024 + threadIdx.x;
    if (i < NN) row_start[i] += offs[blockIdx.x];
}

// ---------------- CSR bucket fill ----------------
__global__ void k_fill_csr(const int* __restrict__ src, const int* __restrict__ dst,
                           const int* __restrict__ row_start, int* __restrict__ fill,
                           int* __restrict__ csr_src, int n) {
    int e = blockIdx.x * blockDim.x + threadIdx.x;
    if (e < n) {
        int d = dst[e];
        int pos = atomicAdd(&fill[d], 1);
        csr_src[row_start[d] + pos] = src[e];
    }
}

// ---------------- norm = max(deg,1)^-0.5 ----------------
__global__ void k_norm(const int* __restrict__ deg, float* __restrict__ norm, int n) {
    int i = blockIdx.x * blockDim.x + threadIdx.x;
    if (i < n) norm[i] = rsqrtf(fmaxf((float)deg[i], 1.0f));
}

// ---------------- converts ----------------
__global__ void k_cvt_h(const float* __restrict__ h, unsigned short* __restrict__ hb) {
    int i = blockIdx.x * 256 + threadIdx.x;
    if (i < NN * HID / 4) {
        float4 v = reinterpret_cast<const float4*>(h)[i];
        ushort4 o;
        o.x = f2bf(v.x); o.y = f2bf(v.y); o.z = f2bf(v.z); o.w = f2bf(v.w);
        reinterpret_cast<ushort4*>(hb)[i] = o;
    }
}

// W[384][128] fp32 -> Wt[128][384] bf16
__global__ void k_cvt_wt(const float* __restrict__ W, unsigned short* __restrict__ Wt) {
    int t = blockIdx.x * 256 + threadIdx.x;
    if (t < 384 * HID) {
        int c = t / 384, k = t % 384;
        Wt[t] = f2bf(W[(size_t)k * HID + c]);
    }
}

// ---------------- propagation (bf16 storage, fp32 accum) ----------------
__global__ __launch_bounds__(256) void k_prop_bf(const unsigned short* __restrict__ x, const float* __restrict__ norm,
                                                 const int* __restrict__ row_start, const int* __restrict__ csr_src,
                                                 unsigned short* __restrict__ y) {
    int node = blockIdx.x * 8 + threadIdx.y;
    if (node >= NN) return;
    int lane = threadIdx.x;
    float a0 = 0.f, a1 = 0.f, a2 = 0.f, a3 = 0.f;
    int s = row_start[node], e = row_start[node + 1];
    int i = s;
    for (; i + 4 <= e; i += 4) {
        int sn0 = csr_src[i], sn1 = csr_src[i + 1], sn2 = csr_src[i + 2], sn3 = csr_src[i + 3];
        float ns0 = norm[sn0], ns1 = norm[sn1], ns2 = norm[sn2], ns3 = norm[sn3];
        ushort4 v0 = *reinterpret_cast<const ushort4*>(x + (size_t)sn0 * HID + lane * 4);
        ushort4 v1 = *reinterpret_cast<const ushort4*>(x + (size_t)sn1 * HID + lane * 4);
        ushort4 v2 = *reinterpret_cast<const ushort4*>(x + (size_t)sn2 * HID + lane * 4);
        ushort4 v3 = *reinterpret_cast<const ushort4*>(x + (size_t)sn3 * HID + lane * 4);
        a0 += ns0 * bf2f(v0.x) + ns1 * bf2f(v1.x) + ns2 * bf2f(v2.x) + ns3 * bf2f(v3.x);
        a1 += ns0 * bf2f(v0.y) + ns1 * bf2f(v1.y) + ns2 * bf2f(v2.y) + ns3 * bf2f(v3.y);
        a2 += ns0 * bf2f(v0.z) + ns1 * bf2f(v1.z) + ns2 * bf2f(v2.z) + ns3 * bf2f(v3.z);
        a3 += ns0 * bf2f(v0.w) + ns1 * bf2f(v1.w) + ns2 * bf2f(v2.w) + ns3 * bf2f(v3.w);
    }
    for (; i < e; ++i) {
        int sn = csr_src[i];
        float ns = norm[sn];
        ushort4 v = *reinterpret_cast<const ushort4*>(x + (size_t)sn * HID + lane * 4);
        a0 += ns * bf2f(v.x); a1 += ns * bf2f(v.y); a2 += ns * bf2f(v.z); a3 += ns * bf2f(v.w);
    }
    float nd = norm[node];
    ushort4 o;
    o.x = f2bf(nd * a0); o.y = f2bf(nd * a1); o.z = f2bf(nd * a2); o.w = f2bf(nd * a3);
    *reinterpret_cast<ushort4*>(y + (size_t)node * HID + lane * 4) = o;
}

// ---------------- MFMA GEMM ----------------
__global__ __launch_bounds__(128) void k_gemm_mfma(const unsigned short* __restrict__ x0,
                                                   const unsigned short* __restrict__ x1,
                                                   const unsigned short* __restrict__ x2,
                                                   const unsigned short* __restrict__ Wt,
                                                   const float* __restrict__ bias,
                                                   unsigned short* __restrict__ y) {
    int tid = threadIdx.x;
    int wave = tid >> 6;
    int lane = tid & 63;
    int r = lane & 15, kg = lane >> 4;
    int row0 = blockIdx.x * 32 + wave * 16;
    const unsigned short* xs[3] = { x0, x1, x2 };

    f32x4 acc[8];
    #pragma unroll
    for (int cf = 0; cf < 8; ++cf) acc[cf] = (f32x4){0.f, 0.f, 0.f, 0.f};

    #pragma unroll
    for (int kseg = 0; kseg < 3; ++kseg) {
        const unsigned short* __restrict__ xp = xs[kseg] + (size_t)(row0 + r) * HID;
        #pragma unroll
        for (int kb = 0; kb < 4; ++kb) {
            bf16x8 afrag = *reinterpret_cast<const bf16x8*>(xp + kb * 32 + kg * 8);
            #pragma unroll
            for (int cf = 0; cf < 8; ++cf) {
                bf16x8 bfrag = *reinterpret_cast<const bf16x8*>(
                    Wt + (size_t)(cf * 16 + r) * 384 + kseg * 128 + kb * 32 + kg * 8);
                acc[cf] = __builtin_amdgcn_mfma_f32_16x16x32_bf16(afrag, bfrag, acc[cf], 0, 0, 0);
            }
        }
    }
    int orow = row0 + (lane >> 4) * 4;
    int colr = lane & 15;
    #pragma unroll
    for (int cf = 0; cf < 8; ++cf) {
        int col = cf * 16 + colr;
        float bb = bias[col];
        #pragma unroll
        for (int v = 0; v < 4; ++v) {
            float val = fmaxf(acc[cf][v] + bb, 0.f);
            y[(size_t)(orow + v) * HID + col] = f2bf(val);
        }
    }
}

// ---------------- segment max pool: 32-row chunks, 1250 blocks ----------------
__global__ __launch_bounds__(128) void k_pool_bf(const unsigned short* __restrict__ Z, const int* __restrict__ gid,
                                                 float* __restrict__ pooled, int n) {
    const int CHUNK = 32;
    int d = threadIdx.x;
    int start = blockIdx.x * CHUNK;
    if (start >= n) return;
    int end = min(start + CHUNK, n);
    float m = 0.0f;
    int cg = gid[start];
    int i = start;
    for (; i + 2 <= end; i += 2) {
        int g0 = gid[i], g1 = gid[i + 1];
        float v0 = bf2f(Z[(size_t)i * HID + d]);
        float v1 = bf2f(Z[(size_t)(i + 1) * HID + d]);
        if (g0 != cg) {
            atomicMax((unsigned int*)&pooled[cg * HID + d], __float_as_uint(m));
            m = 0.0f; cg = g0;
        }
        m = fmaxf(m, v0);
        if (g1 != cg) {
            atomicMax((unsigned int*)&pooled[cg * HID + d], __float_as_uint(m));
            m = 0.0f; cg = g1;
        }
        m = fmaxf(m, v1);
    }
    for (; i < end; ++i) {
        int g = gid[i];
        if (g != cg) {
            atomicMax((unsigned int*)&pooled[cg * HID + d], __float_as_uint(m));
            m = 0.0f; cg = g;
        }
        m = fmaxf(m, bf2f(Z[(size_t)i * HID + d]));
    }
    atomicMax((unsigned int*)&pooled[cg * HID + d], __float_as_uint(m));
}

// ---------------- final head ----------------
__global__ void k_head(const float* __restrict__ pooled, const float* __restrict__ Wc,
                       const float* __restrict__ bc, float* __restrict__ out) {
    int t = threadIdx.x;
    if (t < NGRAPH * NCLS) {
        int g = t / NCLS, c = t % NCLS;
        float acc = bc[c];
        for (int k = 0; k < HID; ++k) acc += pooled[g * HID + k] * Wc[k * NCLS + c];
        out[t] = acc;
    }
}

extern "C" void kernel_launch(void* const* d_in, const int* in_sizes, int n_in,
                              void* d_out, int out_size, void* d_ws, size_t ws_size,
                              hipStream_t stream) {
    const float* h   = (const float*)d_in[0];
    const int*   src = (const int*)d_in[1];
    const int*   dst = (const int*)d_in[2];
    const int*   gid = (const int*)d_in[3];
    const float* W1  = (const float*)d_in[4];
    const float* b1  = (const float*)d_in[5];
    const float* W2  = (const float*)d_in[6];
    const float* b2  = (const float*)d_in[7];
    const float* Wc  = (const float*)d_in[8];
    const float* bc  = (const float*)d_in[9];
    float* out = (float*)d_out;

    char* ws = (char*)d_ws;
    size_t off = 0;
    auto alloc = [&](size_t bytes) { void* p = ws + off; off = (off + bytes + 63) & ~(size_t)63; return p; };
    int*   deg       = (int*)alloc((size_t)NN * 4);
    int*   fill      = (int*)alloc((size_t)NN * 4);
    int*   row_start = (int*)alloc((size_t)(NN + 1) * 4);
    int*   csr_src   = (int*)alloc((size_t)NE * 4);
    float* norm      = (float*)alloc((size_t)NN * 4);
    int*   partial   = (int*)alloc(64 * 4);
    int*   offs      = (int*)alloc(64 * 4);
    float* pooled    = (float*)alloc((size_t)NGRAPH * HID * 4);
    unsigned short* W1t = (unsigned short*)alloc((size_t)384 * HID * 2);
    unsigned short* W2t = (unsigned short*)alloc((size_t)384 * HID * 2);
    unsigned short* hb  = (unsigned short*)alloc((size_t)NN * HID * 2);
    unsigned short* Bb  = (unsigned short*)alloc((size_t)NN * HID * 2);
    unsigned short* Cb  = (unsigned short*)alloc((size_t)NN * HID * 2);
    unsigned short* Yb  = (unsigned short*)alloc((size_t)NN * HID * 2);
    unsigned short* Zb  = (unsigned short*)alloc((size_t)NN * HID * 2);

    hipMemsetAsync(deg, 0, (size_t)NN * 4 * 2, stream);
    hipMemsetAsync(pooled, 0, (size_t)NGRAPH * HID * 4, stream);

    const int EB = 256;
    const int SCAN_BLOCKS = (NN + 1023) / 1024;
    k_count_deg<<<(NE + EB - 1) / EB, EB, 0, stream>>>(dst, deg, NE);
    k_scan1<<<SCAN_BLOCKS, 1024, 0, stream>>>(deg, row_start, partial);
    k_scan2<<<1, 64, 0, stream>>>(partial, offs, row_start, SCAN_BLOCKS);
    k_scan3<<<SCAN_BLOCKS, 1024, 0, stream>>>(row_start, offs);
    k_fill_csr<<<(NE + EB - 1) / EB, EB, 0, stream>>>(src, dst, row_start, fill, csr_src, NE);
    k_norm<<<(NN + EB - 1) / EB, EB, 0, stream>>>(deg, norm, NN);

    k_cvt_h<<<(NN * HID / 4 + 255) / 256, 256, 0, stream>>>(h, hb);
    k_cvt_wt<<<(384 * HID + 255) / 256, 256, 0, stream>>>(W1, W1t);
    k_cvt_wt<<<(384 * HID + 255) / 256, 256, 0, stream>>>(W2, W2t);

    dim3 pblk(32, 8);
    int pblocks = (NN + 7) / 8;
    int gblocks = NN / 32;

    k_prop_bf<<<pblocks, pblk, 0, stream>>>(hb, norm, row_start, csr_src, Bb);
    k_prop_bf<<<pblocks, pblk, 0, stream>>>(Bb, norm, row_start, csr_src, Cb);
    k_gemm_mfma<<<gblocks, 128, 0, stream>>>(hb, Bb, Cb, W1t, b1, Yb);

    k_prop_bf<<<pblocks, pblk, 0, stream>>>(Yb, norm, row_start, csr_src, Bb);
    k_prop_bf<<<pblocks, pblk, 0, stream>>>(Bb, norm, row_start, csr_src, Cb);
    k_gemm_mfma<<<gblocks, 128, 0, stream>>>(Yb, Bb, Cb, W2t, b2, Zb);

    k_pool_bf<<<(NN + 31) / 32, 128, 0, stream>>>(Zb, gid, pooled, NN);
    k_head<<<1, 192, 0, stream>>>(pooled, Wc, bc, out);
}